// Round 1
// baseline (5463.322 us; speedup 1.0000x reference)
//
#include <hip/hip_runtime.h>
#include <math.h>

#define BB 2
#define TT 2048
#define DMODEL 2048
#define NH 32
#define NKV 8
#define HD 64
#define NROWS (BB*TT)   // 4096

// ---------------------------------------------------------------------------
// QKV GEMM: C(4096 x 3072) = x(4096x2048) @ [Wq(2048x2048) | Wk(2048x512) | Wv(2048x512)]
// 64x64 tile per block, 256 threads, each thread 4x4 micro-tile, TK=16.
// ---------------------------------------------------------------------------
__global__ __launch_bounds__(256) void qkv_gemm(
    const float* __restrict__ x, const float* __restrict__ Wq,
    const float* __restrict__ Wk, const float* __restrict__ Wv,
    float* __restrict__ q, float* __restrict__ k, float* __restrict__ v)
{
    __shared__ float As[16][68];   // [k][m], padded for b128-aligned conflict-free reads
    __shared__ float Bs[16][68];   // [k][n]
    const int tid = threadIdx.x;
    const int tx = tid & 15;       // N dir
    const int ty = tid >> 4;       // M dir
    const int mBase = blockIdx.y * 64;
    const int nBase = blockIdx.x * 64;

    const float* W; int wcols; int ncol0; float* dst; int dstride;
    if (nBase < 2048)      { W = Wq; wcols = 2048; ncol0 = nBase;        dst = q; dstride = 2048; }
    else if (nBase < 2560) { W = Wk; wcols = 512;  ncol0 = nBase - 2048; dst = k; dstride = 512; }
    else                   { W = Wv; wcols = 512;  ncol0 = nBase - 2560; dst = v; dstride = 512; }

    float acc[4][4] = {};
    for (int k0 = 0; k0 < 2048; k0 += 16) {
        {   // A tile: 64 rows x 16 k
            const int kk = tid & 15;
            const int r0 = (tid >> 4) * 4;
            #pragma unroll
            for (int i = 0; i < 4; ++i)
                As[kk][r0 + i] = x[(size_t)(mBase + r0 + i) * 2048 + (k0 + kk)];
        }
        {   // B tile: 16 k x 64 n (coalesced 64-wide)
            const int n = tid & 63;
            const int kb = (tid >> 6) * 4;
            #pragma unroll
            for (int i = 0; i < 4; ++i)
                Bs[kb + i][n] = W[(size_t)(k0 + kb + i) * wcols + (ncol0 + n)];
        }
        __syncthreads();
        #pragma unroll
        for (int kk = 0; kk < 16; ++kk) {
            float4 a4 = *(const float4*)&As[kk][ty * 4];
            float4 b4 = *(const float4*)&Bs[kk][tx * 4];
            float a[4] = {a4.x, a4.y, a4.z, a4.w};
            float b[4] = {b4.x, b4.y, b4.z, b4.w};
            #pragma unroll
            for (int i = 0; i < 4; ++i)
                #pragma unroll
                for (int j = 0; j < 4; ++j)
                    acc[i][j] += a[i] * b[j];
        }
        __syncthreads();
    }
    #pragma unroll
    for (int i = 0; i < 4; ++i) {
        int row = mBase + ty * 4 + i;
        float4 o = make_float4(acc[i][0], acc[i][1], acc[i][2], acc[i][3]);
        *(float4*)&dst[(size_t)row * dstride + ncol0 + tx * 4] = o;
    }
}

// ---------------------------------------------------------------------------
// Output GEMM: out(4096x2048) = ctx(4096x2048) @ Wo(2048x2048) + b_out
// ---------------------------------------------------------------------------
__global__ __launch_bounds__(256) void out_gemm(
    const float* __restrict__ ctx, const float* __restrict__ Wo,
    const float* __restrict__ bias, float* __restrict__ out)
{
    __shared__ float As[16][68];
    __shared__ float Bs[16][68];
    const int tid = threadIdx.x;
    const int tx = tid & 15;
    const int ty = tid >> 4;
    const int mBase = blockIdx.y * 64;
    const int nBase = blockIdx.x * 64;

    float acc[4][4] = {};
    for (int k0 = 0; k0 < 2048; k0 += 16) {
        {
            const int kk = tid & 15;
            const int r0 = (tid >> 4) * 4;
            #pragma unroll
            for (int i = 0; i < 4; ++i)
                As[kk][r0 + i] = ctx[(size_t)(mBase + r0 + i) * 2048 + (k0 + kk)];
        }
        {
            const int n = tid & 63;
            const int kb = (tid >> 6) * 4;
            #pragma unroll
            for (int i = 0; i < 4; ++i)
                Bs[kb + i][n] = Wo[(size_t)(k0 + kb + i) * 2048 + (nBase + n)];
        }
        __syncthreads();
        #pragma unroll
        for (int kk = 0; kk < 16; ++kk) {
            float4 a4 = *(const float4*)&As[kk][ty * 4];
            float4 b4 = *(const float4*)&Bs[kk][tx * 4];
            float a[4] = {a4.x, a4.y, a4.z, a4.w};
            float b[4] = {b4.x, b4.y, b4.z, b4.w};
            #pragma unroll
            for (int i = 0; i < 4; ++i)
                #pragma unroll
                for (int j = 0; j < 4; ++j)
                    acc[i][j] += a[i] * b[j];
        }
        __syncthreads();
    }
    #pragma unroll
    for (int i = 0; i < 4; ++i) {
        int row = mBase + ty * 4 + i;
        int col = nBase + tx * 4;
        float4 o = make_float4(acc[i][0] + bias[col + 0], acc[i][1] + bias[col + 1],
                               acc[i][2] + bias[col + 2], acc[i][3] + bias[col + 3]);
        *(float4*)&out[(size_t)row * 2048 + col] = o;
    }
}

// ---------------------------------------------------------------------------
// RoPE in-place on q [4096][32*64] and k [4096][8*64].
// Pair (i, i+32) within each head's 64 dims; angle = t * 10000^(-i/32).
// ---------------------------------------------------------------------------
__global__ void rope_kernel(float* __restrict__ q, float* __restrict__ k)
{
    const int qpairs = NROWS * NH * 32;    // 4,194,304
    const int kpairs = NROWS * NKV * 32;   // 1,048,576
    int idx = blockIdx.x * blockDim.x + threadIdx.x;
    if (idx >= qpairs + kpairs) return;
    float* buf; int stride; int li;
    if (idx < qpairs) { buf = q; stride = 2048; li = idx; }
    else              { buf = k; stride = 512;  li = idx - qpairs; }
    const int i    = li & 31;
    const int hcol = (li >> 5) & ((stride >> 6) - 1);
    const int row  = li / (stride >> 1);       // 32 * n_heads == stride/2
    const int t    = row & (TT - 1);
    // inv_freq = 10000^(-i/32) = exp(-i * ln(10000)/32)
    const float ang = (float)t * expf(-0.28782313662f * (float)i);
    float s, c;
    sincosf(ang, &s, &c);
    size_t base = (size_t)row * stride + hcol * 64 + i;
    float x1 = buf[base], x2 = buf[base + 32];
    buf[base]      = x1 * c - x2 * s;
    buf[base + 32] = x2 * c + x1 * s;
}

// ---------------------------------------------------------------------------
// Causal GQA flash attention. Block = 256 threads, one (b, head, 64-query tile)
// per block. Online softmax; K/V share one LDS buffer (loaded sequentially).
// Scale 1/sqrt(64) folded into Q on load.
// ---------------------------------------------------------------------------
__global__ __launch_bounds__(256) void attn_kernel(
    const float* __restrict__ q, const float* __restrict__ k,
    const float* __restrict__ v, float* __restrict__ ctx)
{
    __shared__ float Qs[64][65];
    __shared__ float KVs[64][65];
    __shared__ float Ss[64][65];
    __shared__ float mrow[64], lrow[64], alpha[64];

    const int qt = blockIdx.x;    // query tile (0..31)
    const int h  = blockIdx.y;    // q head (0..31)
    const int b  = blockIdx.z;
    const int kvh = h >> 2;       // GQA: 4 q-heads per kv-head
    const int tid = threadIdx.x;
    const int cc = tid & 63;
    const int rq = tid >> 6;

    {   // load Q tile, scale by 1/8
        const int c = tid & 63;
        const int r0 = (tid >> 6) * 16;
        for (int i = 0; i < 16; ++i) {
            int r = r0 + i;
            Qs[r][c] = q[((size_t)(b * TT + qt * 64 + r)) * 2048 + h * 64 + c] * 0.125f;
        }
    }
    if (tid < 64) { mrow[tid] = -INFINITY; lrow[tid] = 0.0f; }
    float Oacc[16];
    #pragma unroll
    for (int i = 0; i < 16; ++i) Oacc[i] = 0.0f;
    __syncthreads();

    for (int kt = 0; kt <= qt; ++kt) {
        {   // load K tile
            const int c = tid & 63;
            const int r0 = (tid >> 6) * 16;
            for (int i = 0; i < 16; ++i) {
                int r = r0 + i;
                KVs[r][c] = k[((size_t)(b * TT + kt * 64 + r)) * 512 + kvh * 64 + c];
            }
        }
        __syncthreads();
        {   // S[r][cc] = Q[r]·K[cc]; thread covers rows rq+4i
            float sreg[16];
            #pragma unroll
            for (int i = 0; i < 16; ++i) sreg[i] = 0.0f;
            for (int kk = 0; kk < 64; ++kk) {
                float kval = KVs[cc][kk];
                #pragma unroll
                for (int i = 0; i < 16; ++i)
                    sreg[i] += Qs[rq + 4 * i][kk] * kval;
            }
            const int kidx = kt * 64 + cc;
            #pragma unroll
            for (int i = 0; i < 16; ++i) {
                int r = rq + 4 * i;
                Ss[r][cc] = (kidx <= qt * 64 + r) ? sreg[i] : -INFINITY;
            }
        }
        __syncthreads();
        // online softmax (rows on tid<64) + V load (all threads) in parallel
        if (tid < 64) {
            const int r = tid;
            float m_old = mrow[r];
            float m_new = m_old;
            for (int j = 0; j < 64; ++j) m_new = fmaxf(m_new, Ss[r][j]);
            float al = expf(m_old - m_new);   // exp(-inf)=0 on first tile
            float sum = 0.0f;
            for (int j = 0; j < 64; ++j) {
                float p = expf(Ss[r][j] - m_new);
                Ss[r][j] = p;
                sum += p;
            }
            lrow[r] = lrow[r] * al + sum;
            mrow[r] = m_new;
            alpha[r] = al;
        }
        {   // load V tile into the (now free) K buffer
            const int c = tid & 63;
            const int r0 = (tid >> 6) * 16;
            for (int i = 0; i < 16; ++i) {
                int r = r0 + i;
                KVs[r][c] = v[((size_t)(b * TT + kt * 64 + r)) * 512 + kvh * 64 + c];
            }
        }
        __syncthreads();
        // O = O*alpha + P V
        #pragma unroll
        for (int i = 0; i < 16; ++i) Oacc[i] *= alpha[rq + 4 * i];
        for (int j = 0; j < 64; ++j) {
            float vval = KVs[j][cc];
            #pragma unroll
            for (int i = 0; i < 16; ++i)
                Oacc[i] += Ss[rq + 4 * i][j] * vval;
        }
        __syncthreads();
    }
    // write ctx in [b][t][h][hd] layout (ready for out GEMM)
    #pragma unroll
    for (int i = 0; i < 16; ++i) {
        int r = rq + 4 * i;
        ctx[(((size_t)(b * TT + qt * 64 + r)) * 32 + h) * 64 + cc] = Oacc[i] / lrow[r];
    }
}

extern "C" void kernel_launch(void* const* d_in, const int* in_sizes, int n_in,
                              void* d_out, int out_size, void* d_ws, size_t ws_size,
                              hipStream_t stream) {
    const float* x    = (const float*)d_in[0];
    const float* Wq   = (const float*)d_in[1];
    const float* Wk   = (const float*)d_in[2];
    const float* Wv   = (const float*)d_in[3];
    const float* Wo   = (const float*)d_in[4];
    const float* bout = (const float*)d_in[5];
    float* out = (float*)d_out;

    // workspace layout (floats): q[4096*2048] k[4096*512] v[4096*512] ctx[4096*2048]
    float* qb  = (float*)d_ws;
    float* kb  = qb + (size_t)NROWS * 2048;
    float* vb  = kb + (size_t)NROWS * 512;
    float* ctx = vb + (size_t)NROWS * 512;

    dim3 g1(48, 64);
    qkv_gemm<<<g1, 256, 0, stream>>>(x, Wq, Wk, Wv, qb, kb, vb);

    const int totalPairs = NROWS * NH * 32 + NROWS * NKV * 32;
    rope_kernel<<<(totalPairs + 255) / 256, 256, 0, stream>>>(qb, kb);

    dim3 g3(32, 32, 2);
    attn_kernel<<<g3, 256, 0, stream>>>(qb, kb, vb, ctx);

    dim3 g4(32, 64);
    out_gemm<<<g4, 256, 0, stream>>>(ctx, Wo, bout, out);
}

// Round 2
// 1521.160 us; speedup vs baseline: 3.5916x; 3.5916x over previous
//
#include <hip/hip_runtime.h>
#include <math.h>

#define BB 2
#define TT 2048
#define DMODEL 2048
#define NH 32
#define NKV 8
#define HD 64
#define NROWS (BB*TT)   // 4096

typedef __attribute__((ext_vector_type(4))) float floatx4;
typedef __attribute__((ext_vector_type(8))) short short8;

__device__ __forceinline__ short f2bf(float f) {
    union { float fv; unsigned u; } v; v.fv = f;
    unsigned r = v.u + 0x7FFFu + ((v.u >> 16) & 1u);   // round-to-nearest-even
    return (short)(r >> 16);
}

// ---------------------------------------------------------------------------
// QKV GEMM (fp32 tiled, unchanged from R1)
// ---------------------------------------------------------------------------
__global__ __launch_bounds__(256) void qkv_gemm(
    const float* __restrict__ x, const float* __restrict__ Wq,
    const float* __restrict__ Wk, const float* __restrict__ Wv,
    float* __restrict__ q, float* __restrict__ k, float* __restrict__ v)
{
    __shared__ float As[16][68];
    __shared__ float Bs[16][68];
    const int tid = threadIdx.x;
    const int tx = tid & 15;
    const int ty = tid >> 4;
    const int mBase = blockIdx.y * 64;
    const int nBase = blockIdx.x * 64;

    const float* W; int wcols; int ncol0; float* dst; int dstride;
    if (nBase < 2048)      { W = Wq; wcols = 2048; ncol0 = nBase;        dst = q; dstride = 2048; }
    else if (nBase < 2560) { W = Wk; wcols = 512;  ncol0 = nBase - 2048; dst = k; dstride = 512; }
    else                   { W = Wv; wcols = 512;  ncol0 = nBase - 2560; dst = v; dstride = 512; }

    float acc[4][4] = {};
    for (int k0 = 0; k0 < 2048; k0 += 16) {
        {
            const int kk = tid & 15;
            const int r0 = (tid >> 4) * 4;
            #pragma unroll
            for (int i = 0; i < 4; ++i)
                As[kk][r0 + i] = x[(size_t)(mBase + r0 + i) * 2048 + (k0 + kk)];
        }
        {
            const int n = tid & 63;
            const int kb = (tid >> 6) * 4;
            #pragma unroll
            for (int i = 0; i < 4; ++i)
                Bs[kb + i][n] = W[(size_t)(k0 + kb + i) * wcols + (ncol0 + n)];
        }
        __syncthreads();
        #pragma unroll
        for (int kk = 0; kk < 16; ++kk) {
            float4 a4 = *(const float4*)&As[kk][ty * 4];
            float4 b4 = *(const float4*)&Bs[kk][tx * 4];
            float a[4] = {a4.x, a4.y, a4.z, a4.w};
            float b[4] = {b4.x, b4.y, b4.z, b4.w};
            #pragma unroll
            for (int i = 0; i < 4; ++i)
                #pragma unroll
                for (int j = 0; j < 4; ++j)
                    acc[i][j] += a[i] * b[j];
        }
        __syncthreads();
    }
    #pragma unroll
    for (int i = 0; i < 4; ++i) {
        int row = mBase + ty * 4 + i;
        float4 o = make_float4(acc[i][0], acc[i][1], acc[i][2], acc[i][3]);
        *(float4*)&dst[(size_t)row * dstride + ncol0 + tx * 4] = o;
    }
}

// ---------------------------------------------------------------------------
// Output GEMM (fp32 tiled, unchanged from R1)
// ---------------------------------------------------------------------------
__global__ __launch_bounds__(256) void out_gemm(
    const float* __restrict__ ctx, const float* __restrict__ Wo,
    const float* __restrict__ bias, float* __restrict__ out)
{
    __shared__ float As[16][68];
    __shared__ float Bs[16][68];
    const int tid = threadIdx.x;
    const int tx = tid & 15;
    const int ty = tid >> 4;
    const int mBase = blockIdx.y * 64;
    const int nBase = blockIdx.x * 64;

    float acc[4][4] = {};
    for (int k0 = 0; k0 < 2048; k0 += 16) {
        {
            const int kk = tid & 15;
            const int r0 = (tid >> 4) * 4;
            #pragma unroll
            for (int i = 0; i < 4; ++i)
                As[kk][r0 + i] = ctx[(size_t)(mBase + r0 + i) * 2048 + (k0 + kk)];
        }
        {
            const int n = tid & 63;
            const int kb = (tid >> 6) * 4;
            #pragma unroll
            for (int i = 0; i < 4; ++i)
                Bs[kb + i][n] = Wo[(size_t)(k0 + kb + i) * 2048 + (nBase + n)];
        }
        __syncthreads();
        #pragma unroll
        for (int kk = 0; kk < 16; ++kk) {
            float4 a4 = *(const float4*)&As[kk][ty * 4];
            float4 b4 = *(const float4*)&Bs[kk][tx * 4];
            float a[4] = {a4.x, a4.y, a4.z, a4.w};
            float b[4] = {b4.x, b4.y, b4.z, b4.w};
            #pragma unroll
            for (int i = 0; i < 4; ++i)
                #pragma unroll
                for (int j = 0; j < 4; ++j)
                    acc[i][j] += a[i] * b[j];
        }
        __syncthreads();
    }
    #pragma unroll
    for (int i = 0; i < 4; ++i) {
        int row = mBase + ty * 4 + i;
        int col = nBase + tx * 4;
        float4 o = make_float4(acc[i][0] + bias[col + 0], acc[i][1] + bias[col + 1],
                               acc[i][2] + bias[col + 2], acc[i][3] + bias[col + 3]);
        *(float4*)&out[(size_t)row * 2048 + col] = o;
    }
}

// ---------------------------------------------------------------------------
// RoPE in-place (unchanged from R1)
// ---------------------------------------------------------------------------
__global__ void rope_kernel(float* __restrict__ q, float* __restrict__ k)
{
    const int qpairs = NROWS * NH * 32;
    const int kpairs = NROWS * NKV * 32;
    int idx = blockIdx.x * blockDim.x + threadIdx.x;
    if (idx >= qpairs + kpairs) return;
    float* buf; int stride; int li;
    if (idx < qpairs) { buf = q; stride = 2048; li = idx; }
    else              { buf = k; stride = 512;  li = idx - qpairs; }
    const int i    = li & 31;
    const int hcol = (li >> 5) & ((stride >> 6) - 1);
    const int row  = li / (stride >> 1);
    const int t    = row & (TT - 1);
    const float ang = (float)t * expf(-0.28782313662f * (float)i);
    float s, c;
    sincosf(ang, &s, &c);
    size_t base = (size_t)row * stride + hcol * 64 + i;
    float x1 = buf[base], x2 = buf[base + 32];
    buf[base]      = x1 * c - x2 * s;
    buf[base + 32] = x2 * c + x1 * s;
}

// ---------------------------------------------------------------------------
// Causal GQA flash attention, bf16 MFMA (16x16x32).
// Block = 256 threads = 4 waves; one (b, head, 64-query tile) per block.
// Wave w owns Q rows [w*16, w*16+16). Per K-tile:
//   S strip (16x64) = 8 MFMAs; online softmax in registers (C-layout rows
//   live in regs; reduce across the 16-lane col group via shfl_xor);
//   P -> LDS (C-layout -> A-layout transform); PV strip = 8 MFMAs.
// Ks stored [key][dim] (B^T pattern); Vt stored transposed [hd][key].
// ---------------------------------------------------------------------------
#define LDH 72   // row stride in bf16 elems: 144 B, 16B-aligned, bank-skewed

__global__ __launch_bounds__(256) void attn_mfma(
    const float* __restrict__ q, const float* __restrict__ k,
    const float* __restrict__ v, float* __restrict__ ctx)
{
    __shared__ short Qs[64 * LDH];
    __shared__ short Ks[64 * LDH];
    __shared__ short Vt[64 * LDH];
    __shared__ short Ps[64 * LDH];

    const int qt = blockIdx.x, h = blockIdx.y, b = blockIdx.z;
    const int kvh = h >> 2;
    const int tid = threadIdx.x;
    const int lane = tid & 63, wave = tid >> 6;
    const int l15 = lane & 15, quad = lane >> 4;
    const int strip = wave * 16;

    // ---- stage Q tile: row = tid>>2, dims (tid&3)*16..+15; scale 1/sqrt(64)
    {
        const int row = tid >> 2, doff = (tid & 3) * 16;
        const float* src = q + ((size_t)(b * TT + qt * 64 + row)) * 2048 + h * 64 + doff;
        float fv[16];
        *(float4*)&fv[0]  = *(const float4*)(src);
        *(float4*)&fv[4]  = *(const float4*)(src + 4);
        *(float4*)&fv[8]  = *(const float4*)(src + 8);
        *(float4*)&fv[12] = *(const float4*)(src + 12);
        short8 sa, sb;
        #pragma unroll
        for (int j = 0; j < 8; ++j) {
            sa[j] = f2bf(fv[j] * 0.125f);
            sb[j] = f2bf(fv[j + 8] * 0.125f);
        }
        *(short8*)&Qs[row * LDH + doff]     = sa;
        *(short8*)&Qs[row * LDH + doff + 8] = sb;
    }

    float m_i[4], l_i[4];
    floatx4 oacc[4];
    #pragma unroll
    for (int r = 0; r < 4; ++r) { m_i[r] = -INFINITY; l_i[r] = 0.0f; }
    #pragma unroll
    for (int tc = 0; tc < 4; ++tc) oacc[tc] = (floatx4){0.f, 0.f, 0.f, 0.f};

    // Q fragments: wave reads only its own strip (rows it staged itself;
    // same-wave DS ops are in-order, no barrier needed). Hoisted out of loop.
    short8 qf0 = *(short8*)&Qs[(strip + l15) * LDH + quad * 8];
    short8 qf1 = *(short8*)&Qs[(strip + l15) * LDH + 32 + quad * 8];

    for (int kt = 0; kt <= qt; ++kt) {
        __syncthreads();   // prior iter's Ks/Vt reads complete before overwrite
        // ---- stage K tile [key][dim]
        {
            const int row = tid >> 2, doff = (tid & 3) * 16;
            const float* src = k + ((size_t)(b * TT + kt * 64 + row)) * 512 + kvh * 64 + doff;
            float fv[16];
            *(float4*)&fv[0]  = *(const float4*)(src);
            *(float4*)&fv[4]  = *(const float4*)(src + 4);
            *(float4*)&fv[8]  = *(const float4*)(src + 8);
            *(float4*)&fv[12] = *(const float4*)(src + 12);
            short8 sa, sb;
            #pragma unroll
            for (int j = 0; j < 8; ++j) { sa[j] = f2bf(fv[j]); sb[j] = f2bf(fv[j + 8]); }
            *(short8*)&Ks[row * LDH + doff]     = sa;
            *(short8*)&Ks[row * LDH + doff + 8] = sb;
        }
        // ---- stage V tile transposed [hd][key]; keys 2kp,2kp+1 packed per b32
        {
            const int kp = tid & 31, doff = (tid >> 5) * 8;
            const float* s0 = v + ((size_t)(b * TT + kt * 64 + 2 * kp)) * 512 + kvh * 64 + doff;
            const float* s1 = s0 + 512;
            float a0[8], a1[8];
            *(float4*)&a0[0] = *(const float4*)(s0);
            *(float4*)&a0[4] = *(const float4*)(s0 + 4);
            *(float4*)&a1[0] = *(const float4*)(s1);
            *(float4*)&a1[4] = *(const float4*)(s1 + 4);
            #pragma unroll
            for (int j = 0; j < 8; ++j) {
                unsigned lo = (unsigned short)f2bf(a0[j]);
                unsigned hi = (unsigned short)f2bf(a1[j]);
                *(unsigned*)&Vt[(doff + j) * LDH + 2 * kp] = lo | (hi << 16);
            }
        }
        __syncthreads();

        // ---- S strip = Q(16x64) . K^T(64x64), 4 col tiles x 2 K-chunks
        floatx4 sacc[4];
        #pragma unroll
        for (int tc = 0; tc < 4; ++tc) sacc[tc] = (floatx4){0.f, 0.f, 0.f, 0.f};
        #pragma unroll
        for (int tc = 0; tc < 4; ++tc) {
            short8 kf0 = *(short8*)&Ks[(tc * 16 + l15) * LDH + quad * 8];
            short8 kf1 = *(short8*)&Ks[(tc * 16 + l15) * LDH + 32 + quad * 8];
            sacc[tc] = __builtin_amdgcn_mfma_f32_16x16x32_bf16(qf0, kf0, sacc[tc], 0, 0, 0);
            sacc[tc] = __builtin_amdgcn_mfma_f32_16x16x32_bf16(qf1, kf1, sacc[tc], 0, 0, 0);
        }
        // ---- causal mask (diag tile only): C layout row=quad*4+r, col=tc*16+l15
        if (kt == qt) {
            #pragma unroll
            for (int tc = 0; tc < 4; ++tc)
                #pragma unroll
                for (int r = 0; r < 4; ++r)
                    if (tc * 16 + l15 > strip + quad * 4 + r) sacc[tc][r] = -INFINITY;
        }
        // ---- online softmax in registers
        float rmax[4];
        #pragma unroll
        for (int r = 0; r < 4; ++r) {
            rmax[r] = fmaxf(fmaxf(sacc[0][r], sacc[1][r]), fmaxf(sacc[2][r], sacc[3][r]));
        }
        #pragma unroll
        for (int off = 1; off < 16; off <<= 1)
            #pragma unroll
            for (int r = 0; r < 4; ++r)
                rmax[r] = fmaxf(rmax[r], __shfl_xor(rmax[r], off, 64));
        float al[4];
        #pragma unroll
        for (int r = 0; r < 4; ++r) {
            float mn = fmaxf(m_i[r], rmax[r]);
            al[r] = __expf(m_i[r] - mn);   // exp(-inf)=0 on first tile
            m_i[r] = mn;
        }
        float rsum[4] = {0.f, 0.f, 0.f, 0.f};
        #pragma unroll
        for (int tc = 0; tc < 4; ++tc)
            #pragma unroll
            for (int r = 0; r < 4; ++r) {
                float p = __expf(sacc[tc][r] - m_i[r]);
                sacc[tc][r] = p;
                rsum[r] += p;
            }
        // ---- write P (C-layout -> row-major LDS; read back below in A-layout)
        #pragma unroll
        for (int tc = 0; tc < 4; ++tc)
            #pragma unroll
            for (int r = 0; r < 4; ++r)
                Ps[(strip + quad * 4 + r) * LDH + tc * 16 + l15] = f2bf(sacc[tc][r]);
        #pragma unroll
        for (int off = 1; off < 16; off <<= 1)
            #pragma unroll
            for (int r = 0; r < 4; ++r)
                rsum[r] += __shfl_xor(rsum[r], off, 64);
        #pragma unroll
        for (int r = 0; r < 4; ++r) l_i[r] = l_i[r] * al[r] + rsum[r];
        #pragma unroll
        for (int tc = 0; tc < 4; ++tc)
            #pragma unroll
            for (int r = 0; r < 4; ++r)
                oacc[tc][r] *= al[r];
        // ---- O += P(16x64) . V(64x64)
        short8 pf0 = *(short8*)&Ps[(strip + l15) * LDH + quad * 8];
        short8 pf1 = *(short8*)&Ps[(strip + l15) * LDH + 32 + quad * 8];
        #pragma unroll
        for (int tc = 0; tc < 4; ++tc) {
            short8 vf0 = *(short8*)&Vt[(tc * 16 + l15) * LDH + quad * 8];
            short8 vf1 = *(short8*)&Vt[(tc * 16 + l15) * LDH + 32 + quad * 8];
            oacc[tc] = __builtin_amdgcn_mfma_f32_16x16x32_bf16(pf0, vf0, oacc[tc], 0, 0, 0);
            oacc[tc] = __builtin_amdgcn_mfma_f32_16x16x32_bf16(pf1, vf1, oacc[tc], 0, 0, 0);
        }
    }
    // ---- epilogue: ctx[b][t][h][hd]
    #pragma unroll
    for (int tc = 0; tc < 4; ++tc)
        #pragma unroll
        for (int r = 0; r < 4; ++r) {
            int row = qt * 64 + strip + quad * 4 + r;
            ctx[((size_t)(b * TT + row) * 32 + h) * 64 + tc * 16 + l15] = oacc[tc][r] / l_i[r];
        }
}

extern "C" void kernel_launch(void* const* d_in, const int* in_sizes, int n_in,
                              void* d_out, int out_size, void* d_ws, size_t ws_size,
                              hipStream_t stream) {
    const float* x    = (const float*)d_in[0];
    const float* Wq   = (const float*)d_in[1];
    const float* Wk   = (const float*)d_in[2];
    const float* Wv   = (const float*)d_in[3];
    const float* Wo   = (const float*)d_in[4];
    const float* bout = (const float*)d_in[5];
    float* out = (float*)d_out;

    float* qb  = (float*)d_ws;
    float* kb  = qb + (size_t)NROWS * 2048;
    float* vb  = kb + (size_t)NROWS * 512;
    float* ctx = vb + (size_t)NROWS * 512;

    dim3 g1(48, 64);
    qkv_gemm<<<g1, 256, 0, stream>>>(x, Wq, Wk, Wv, qb, kb, vb);

    const int totalPairs = NROWS * NH * 32 + NROWS * NKV * 32;
    rope_kernel<<<(totalPairs + 255) / 256, 256, 0, stream>>>(qb, kb);

    dim3 g3(32, 32, 2);
    attn_mfma<<<g3, 256, 0, stream>>>(qb, kb, vb, ctx);

    dim3 g4(32, 64);
    out_gemm<<<g4, 256, 0, stream>>>(ctx, Wo, bout, out);
}

// Round 3
// 494.263 us; speedup vs baseline: 11.0535x; 3.0776x over previous
//
#include <hip/hip_runtime.h>
#include <math.h>

#define BB 2
#define TT 2048
#define NH 32
#define NKV 8
#define NROWS 4096

typedef __attribute__((ext_vector_type(4))) float floatx4;
typedef __attribute__((ext_vector_type(8))) short short8;

__device__ __forceinline__ short f2bf(float f) {
    union { float fv; unsigned u; } v; v.fv = f;
    unsigned r = v.u + 0x7FFFu + ((v.u >> 16) & 1u);   // RNE
    return (short)(r >> 16);
}
__device__ __forceinline__ float bf2f(short s) {
    union { float fv; unsigned u; } v;
    v.u = ((unsigned)(unsigned short)s) << 16;
    return v.fv;
}
__device__ __forceinline__ void gld16(const short* g, short* l) {
    __builtin_amdgcn_global_load_lds((const __attribute__((address_space(1))) void*)g,
                                     (__attribute__((address_space(3))) void*)l, 16, 0, 0);
}

// ---------------------------------------------------------------------------
// fp32 -> bf16 elementwise (for x)
// ---------------------------------------------------------------------------
__global__ void convert_bf16(const float* __restrict__ src, short* __restrict__ dst, int n)
{
    int idx = (blockIdx.x * blockDim.x + threadIdx.x) * 8;
    if (idx >= n) return;
    float4 a = *(const float4*)(src + idx);
    float4 b = *(const float4*)(src + idx + 4);
    short8 o;
    o[0] = f2bf(a.x); o[1] = f2bf(a.y); o[2] = f2bf(a.z); o[3] = f2bf(a.w);
    o[4] = f2bf(b.x); o[5] = f2bf(b.y); o[6] = f2bf(b.z); o[7] = f2bf(b.w);
    *(short8*)(dst + idx) = o;
}

// ---------------------------------------------------------------------------
// fp32 [K][N] -> bf16 [N][K] transpose-convert (weights -> B^T layout)
// ---------------------------------------------------------------------------
__global__ __launch_bounds__(256) void transpose_conv(
    const float* __restrict__ src, short* __restrict__ dst, int K, int N)
{
    __shared__ short T[32][34];
    const int tx = threadIdx.x & 31, ty = threadIdx.x >> 5;
    const int i0 = blockIdx.y * 32, j0 = blockIdx.x * 32;
    #pragma unroll
    for (int i = 0; i < 4; ++i)
        T[ty + 8 * i][tx] = f2bf(src[(size_t)(i0 + ty + 8 * i) * N + j0 + tx]);
    __syncthreads();
    #pragma unroll
    for (int i = 0; i < 4; ++i)
        dst[(size_t)(j0 + ty + 8 * i) * K + i0 + tx] = T[tx][ty + 8 * i];
}

// ---------------------------------------------------------------------------
// bf16 MFMA GEMM, m97 structure: 128x128 tile, BK=32, global_load_lds(16B).
// A [M][2048] bf16, BT [N][2048] bf16. 4 waves; wave = 64x64 quadrant.
// Shared body; two epilogues (QKV split-store bf16 / out fp32+bias).
// ---------------------------------------------------------------------------
#define GEMM_BODY(A_, BT_)                                                           \
    __shared__ short As[128 * 32];                                                   \
    __shared__ short Bs[128 * 32];                                                   \
    const int tid = threadIdx.x, lane = tid & 63, wave = tid >> 6;                   \
    const int l15 = lane & 15, quad = lane >> 4;                                     \
    const int mBase = blockIdx.y * 128, nBase = blockIdx.x * 128;                    \
    const int wRow = (wave >> 1) * 64, wCol = (wave & 1) * 64;                       \
    const int s0 = wave * 2, s1 = wave * 2 + 1;                                      \
    const short* gA0 = A_ + (size_t)(mBase + s0 * 16 + (lane >> 2)) * 2048 + (lane & 3) * 8; \
    const short* gA1 = A_ + (size_t)(mBase + s1 * 16 + (lane >> 2)) * 2048 + (lane & 3) * 8; \
    const short* gB0 = BT_ + (size_t)(nBase + s0 * 16 + (lane >> 2)) * 2048 + (lane & 3) * 8; \
    const short* gB1 = BT_ + (size_t)(nBase + s1 * 16 + (lane >> 2)) * 2048 + (lane & 3) * 8; \
    short* lA0 = &As[s0 * 512]; short* lA1 = &As[s1 * 512];                          \
    short* lB0 = &Bs[s0 * 512]; short* lB1 = &Bs[s1 * 512];                          \
    floatx4 acc[4][4];                                                               \
    _Pragma("unroll") for (int mt = 0; mt < 4; ++mt)                                 \
        _Pragma("unroll") for (int nt = 0; nt < 4; ++nt)                             \
            acc[mt][nt] = (floatx4){0.f, 0.f, 0.f, 0.f};                             \
    for (int k0 = 0; k0 < 2048; k0 += 32) {                                          \
        gld16(gA0 + k0, lA0);                                                        \
        gld16(gA1 + k0, lA1);                                                        \
        gld16(gB0 + k0, lB0);                                                        \
        gld16(gB1 + k0, lB1);                                                        \
        __syncthreads();                                                             \
        short8 af[4], bfr[4];                                                        \
        _Pragma("unroll") for (int mt = 0; mt < 4; ++mt)                             \
            af[mt] = *(short8*)&As[(wRow + mt * 16 + l15) * 32 + quad * 8];          \
        _Pragma("unroll") for (int nt = 0; nt < 4; ++nt)                             \
            bfr[nt] = *(short8*)&Bs[(wCol + nt * 16 + l15) * 32 + quad * 8];         \
        _Pragma("unroll") for (int mt = 0; mt < 4; ++mt)                             \
            _Pragma("unroll") for (int nt = 0; nt < 4; ++nt)                         \
                acc[mt][nt] = __builtin_amdgcn_mfma_f32_16x16x32_bf16(               \
                    af[mt], bfr[nt], acc[mt][nt], 0, 0, 0);                          \
        __syncthreads();                                                             \
    }

__global__ __launch_bounds__(256) void gemm_qkv(
    const short* __restrict__ A, const short* __restrict__ BT,
    short* __restrict__ q, short* __restrict__ kout, short* __restrict__ vout)
{
    GEMM_BODY(A, BT)
    #pragma unroll
    for (int mt = 0; mt < 4; ++mt)
        #pragma unroll
        for (int nt = 0; nt < 4; ++nt) {
            const int n = nBase + wCol + nt * 16 + l15;
            #pragma unroll
            for (int r = 0; r < 4; ++r) {
                const int m = mBase + wRow + mt * 16 + quad * 4 + r;
                short val = f2bf(acc[mt][nt][r]);
                if (n < 2048)      q[(size_t)m * 2048 + n] = val;
                else if (n < 2560) kout[(size_t)m * 512 + n - 2048] = val;
                else               vout[(size_t)m * 512 + n - 2560] = val;
            }
        }
}

__global__ __launch_bounds__(256) void gemm_out(
    const short* __restrict__ A, const short* __restrict__ BT,
    const float* __restrict__ bias, float* __restrict__ out)
{
    GEMM_BODY(A, BT)
    #pragma unroll
    for (int mt = 0; mt < 4; ++mt)
        #pragma unroll
        for (int nt = 0; nt < 4; ++nt) {
            const int n = nBase + wCol + nt * 16 + l15;
            const float bv = bias[n];
            #pragma unroll
            for (int r = 0; r < 4; ++r) {
                const int m = mBase + wRow + mt * 16 + quad * 4 + r;
                out[(size_t)m * 2048 + n] = acc[mt][nt][r] + bv;
            }
        }
}

// ---------------------------------------------------------------------------
// RoPE in-place on bf16 q [4096][2048], k [4096][512].
// ---------------------------------------------------------------------------
__global__ void rope_kernel(short* __restrict__ q, short* __restrict__ k)
{
    const int qpairs = NROWS * NH * 32;
    const int kpairs = NROWS * NKV * 32;
    int idx = blockIdx.x * blockDim.x + threadIdx.x;
    if (idx >= qpairs + kpairs) return;
    short* buf; int stride; int li;
    if (idx < qpairs) { buf = q; stride = 2048; li = idx; }
    else              { buf = k; stride = 512;  li = idx - qpairs; }
    const int i    = li & 31;
    const int hcol = (li >> 5) & ((stride >> 6) - 1);
    const int row  = li / (stride >> 1);
    const int t    = row & (TT - 1);
    const float ang = (float)t * expf(-0.28782313662f * (float)i);
    float s, c;
    sincosf(ang, &s, &c);
    size_t base = (size_t)row * stride + hcol * 64 + i;
    float x1 = bf2f(buf[base]), x2 = bf2f(buf[base + 32]);
    buf[base]      = f2bf(x1 * c - x2 * s);
    buf[base + 32] = f2bf(x2 * c + x1 * s);
}

// ---------------------------------------------------------------------------
// Causal GQA flash attention, bf16 MFMA (R2-verified structure; bf16 inputs,
// scale folded into sacc post-MFMA, bf16 ctx output).
// ---------------------------------------------------------------------------
#define LDH 72

__global__ __launch_bounds__(256) void attn_mfma(
    const short* __restrict__ q, const short* __restrict__ k,
    const short* __restrict__ v, short* __restrict__ ctx)
{
    __shared__ short Qs[64 * LDH];
    __shared__ short Ks[64 * LDH];
    __shared__ short Vt[64 * LDH];
    __shared__ short Ps[64 * LDH];

    const int qt = blockIdx.x, h = blockIdx.y, b = blockIdx.z;
    const int kvh = h >> 2;
    const int tid = threadIdx.x;
    const int lane = tid & 63, wave = tid >> 6;
    const int l15 = lane & 15, quad = lane >> 4;
    const int strip = wave * 16;

    {   // stage Q tile (pure bf16 copy)
        const int row = tid >> 2, doff = (tid & 3) * 16;
        const short* src = q + ((size_t)(b * TT + qt * 64 + row)) * 2048 + h * 64 + doff;
        *(short8*)&Qs[row * LDH + doff]     = *(const short8*)(src);
        *(short8*)&Qs[row * LDH + doff + 8] = *(const short8*)(src + 8);
    }

    float m_i[4], l_i[4];
    floatx4 oacc[4];
    #pragma unroll
    for (int r = 0; r < 4; ++r) { m_i[r] = -INFINITY; l_i[r] = 0.0f; }
    #pragma unroll
    for (int tc = 0; tc < 4; ++tc) oacc[tc] = (floatx4){0.f, 0.f, 0.f, 0.f};

    // wave reads only rows it staged itself (same-wave DS in-order)
    short8 qf0 = *(short8*)&Qs[(strip + l15) * LDH + quad * 8];
    short8 qf1 = *(short8*)&Qs[(strip + l15) * LDH + 32 + quad * 8];

    for (int kt = 0; kt <= qt; ++kt) {
        __syncthreads();
        {   // stage K tile [key][dim]
            const int row = tid >> 2, doff = (tid & 3) * 16;
            const short* src = k + ((size_t)(b * TT + kt * 64 + row)) * 512 + kvh * 64 + doff;
            *(short8*)&Ks[row * LDH + doff]     = *(const short8*)(src);
            *(short8*)&Ks[row * LDH + doff + 8] = *(const short8*)(src + 8);
        }
        {   // stage V transposed [hd][key], packed pairs
            const int kp = tid & 31, doff = (tid >> 5) * 8;
            const short* sp0 = v + ((size_t)(b * TT + kt * 64 + 2 * kp)) * 512 + kvh * 64 + doff;
            short8 a0 = *(const short8*)(sp0);
            short8 a1 = *(const short8*)(sp0 + 512);
            #pragma unroll
            for (int j = 0; j < 8; ++j) {
                unsigned lo = (unsigned short)a0[j];
                unsigned hi = (unsigned short)a1[j];
                *(unsigned*)&Vt[(doff + j) * LDH + 2 * kp] = lo | (hi << 16);
            }
        }
        __syncthreads();

        // S strip = Q(16x64) . K^T
        floatx4 sacc[4];
        #pragma unroll
        for (int tc = 0; tc < 4; ++tc) sacc[tc] = (floatx4){0.f, 0.f, 0.f, 0.f};
        #pragma unroll
        for (int tc = 0; tc < 4; ++tc) {
            short8 kf0 = *(short8*)&Ks[(tc * 16 + l15) * LDH + quad * 8];
            short8 kf1 = *(short8*)&Ks[(tc * 16 + l15) * LDH + 32 + quad * 8];
            sacc[tc] = __builtin_amdgcn_mfma_f32_16x16x32_bf16(qf0, kf0, sacc[tc], 0, 0, 0);
            sacc[tc] = __builtin_amdgcn_mfma_f32_16x16x32_bf16(qf1, kf1, sacc[tc], 0, 0, 0);
        }
        // scale 1/sqrt(64) then causal mask (diag tile only)
        #pragma unroll
        for (int tc = 0; tc < 4; ++tc)
            #pragma unroll
            for (int r = 0; r < 4; ++r)
                sacc[tc][r] *= 0.125f;
        if (kt == qt) {
            #pragma unroll
            for (int tc = 0; tc < 4; ++tc)
                #pragma unroll
                for (int r = 0; r < 4; ++r)
                    if (tc * 16 + l15 > strip + quad * 4 + r) sacc[tc][r] = -INFINITY;
        }
        // online softmax in registers
        float rmax[4];
        #pragma unroll
        for (int r = 0; r < 4; ++r)
            rmax[r] = fmaxf(fmaxf(sacc[0][r], sacc[1][r]), fmaxf(sacc[2][r], sacc[3][r]));
        #pragma unroll
        for (int off = 1; off < 16; off <<= 1)
            #pragma unroll
            for (int r = 0; r < 4; ++r)
                rmax[r] = fmaxf(rmax[r], __shfl_xor(rmax[r], off, 64));
        float al[4];
        #pragma unroll
        for (int r = 0; r < 4; ++r) {
            float mn = fmaxf(m_i[r], rmax[r]);
            al[r] = __expf(m_i[r] - mn);
            m_i[r] = mn;
        }
        float rsum[4] = {0.f, 0.f, 0.f, 0.f};
        #pragma unroll
        for (int tc = 0; tc < 4; ++tc)
            #pragma unroll
            for (int r = 0; r < 4; ++r) {
                float p = __expf(sacc[tc][r] - m_i[r]);
                sacc[tc][r] = p;
                rsum[r] += p;
            }
        #pragma unroll
        for (int tc = 0; tc < 4; ++tc)
            #pragma unroll
            for (int r = 0; r < 4; ++r)
                Ps[(strip + quad * 4 + r) * LDH + tc * 16 + l15] = f2bf(sacc[tc][r]);
        #pragma unroll
        for (int off = 1; off < 16; off <<= 1)
            #pragma unroll
            for (int r = 0; r < 4; ++r)
                rsum[r] += __shfl_xor(rsum[r], off, 64);
        #pragma unroll
        for (int r = 0; r < 4; ++r) l_i[r] = l_i[r] * al[r] + rsum[r];
        #pragma unroll
        for (int tc = 0; tc < 4; ++tc)
            #pragma unroll
            for (int r = 0; r < 4; ++r)
                oacc[tc][r] *= al[r];
        // O += P . V
        short8 pf0 = *(short8*)&Ps[(strip + l15) * LDH + quad * 8];
        short8 pf1 = *(short8*)&Ps[(strip + l15) * LDH + 32 + quad * 8];
        #pragma unroll
        for (int tc = 0; tc < 4; ++tc) {
            short8 vf0 = *(short8*)&Vt[(tc * 16 + l15) * LDH + quad * 8];
            short8 vf1 = *(short8*)&Vt[(tc * 16 + l15) * LDH + 32 + quad * 8];
            oacc[tc] = __builtin_amdgcn_mfma_f32_16x16x32_bf16(pf0, vf0, oacc[tc], 0, 0, 0);
            oacc[tc] = __builtin_amdgcn_mfma_f32_16x16x32_bf16(pf1, vf1, oacc[tc], 0, 0, 0);
        }
    }
    // epilogue: ctx[b][t][h][hd] bf16
    #pragma unroll
    for (int tc = 0; tc < 4; ++tc)
        #pragma unroll
        for (int r = 0; r < 4; ++r) {
            int row = qt * 64 + strip + quad * 4 + r;
            ctx[((size_t)(b * TT + row) * 32 + h) * 64 + tc * 16 + l15] =
                f2bf(oacc[tc][r] / l_i[r]);
        }
}

extern "C" void kernel_launch(void* const* d_in, const int* in_sizes, int n_in,
                              void* d_out, int out_size, void* d_ws, size_t ws_size,
                              hipStream_t stream) {
    const float* x    = (const float*)d_in[0];
    const float* Wq   = (const float*)d_in[1];
    const float* Wk   = (const float*)d_in[2];
    const float* Wv   = (const float*)d_in[3];
    const float* Wo   = (const float*)d_in[4];
    const float* bout = (const float*)d_in[5];
    float* out = (float*)d_out;

    // workspace (shorts): xb | WqkvT | WoT | qb | kb | vb | ctx  = 79.7 MB
    short* xb    = (short*)d_ws;
    short* WqkvT = xb + (size_t)8388608;
    short* WoT   = WqkvT + (size_t)6291456;
    short* qb    = WoT + (size_t)4194304;
    short* kb    = qb + (size_t)8388608;
    short* vb    = kb + (size_t)2097152;
    short* ctx   = vb + (size_t)2097152;

    // conversions
    convert_bf16<<<4096, 256, 0, stream>>>(x, xb, 8388608);
    transpose_conv<<<dim3(64, 64), 256, 0, stream>>>(Wq, WqkvT, 2048, 2048);
    transpose_conv<<<dim3(16, 64), 256, 0, stream>>>(Wk, WqkvT + (size_t)2048 * 2048, 2048, 512);
    transpose_conv<<<dim3(16, 64), 256, 0, stream>>>(Wv, WqkvT + (size_t)2560 * 2048, 2048, 512);
    transpose_conv<<<dim3(64, 64), 256, 0, stream>>>(Wo, WoT, 2048, 2048);

    // QKV GEMM (bf16 MFMA)
    gemm_qkv<<<dim3(24, 32), 256, 0, stream>>>(xb, WqkvT, qb, kb, vb);

    const int totalPairs = NROWS * NH * 32 + NROWS * NKV * 32;
    rope_kernel<<<(totalPairs + 255) / 256, 256, 0, stream>>>(qb, kb);

    attn_mfma<<<dim3(32, 32, 2), 256, 0, stream>>>(qb, kb, vb, ctx);

    // output GEMM (bf16 MFMA) + bias
    gemm_out<<<dim3(16, 32), 256, 0, stream>>>(ctx, WoT, bout, out);
}